// Round 1
// baseline (2125.190 us; speedup 1.0000x reference)
//
#include <hip/hip_runtime.h>

#define TSEQ 4096
#define CEMB 768
#define NHEAD 12

__device__ __forceinline__ float warp_max16(float v) {
    v = fmaxf(v, __shfl_xor(v, 1));
    v = fmaxf(v, __shfl_xor(v, 2));
    v = fmaxf(v, __shfl_xor(v, 4));
    v = fmaxf(v, __shfl_xor(v, 8));
    return v;
}
__device__ __forceinline__ float warp_sum16(float v) {
    v += __shfl_xor(v, 1);
    v += __shfl_xor(v, 2);
    v += __shfl_xor(v, 4);
    v += __shfl_xor(v, 8);
    return v;
}

// C[m][n] = sum_k A[m][k]*B[k][n] + bias[n]
// 128x128 tile, BK=16, 256 threads, 8x8 micro-tile as 2x2 quadrants of 4x4.
__global__ __launch_bounds__(256) void gemm_bias(
    const float* __restrict__ A, const float* __restrict__ B,
    const float* __restrict__ bias, float* __restrict__ C,
    int M, int N, int K, int lda, int ldb, int ldc)
{
    __shared__ float As[16][132];   // [k][m], pad 132 -> 2-way max on transpose store
    __shared__ float Bs[16][128];   // [k][n]
    const int t = threadIdx.x;
    const int tx = t & 15, ty = t >> 4;
    const int m0 = blockIdx.y * 128, n0 = blockIdx.x * 128;

    float acc[8][8];
#pragma unroll
    for (int i = 0; i < 8; ++i)
#pragma unroll
        for (int j = 0; j < 8; ++j) acc[i][j] = 0.f;

    for (int k0 = 0; k0 < K; k0 += 16) {
#pragma unroll
        for (int it = 0; it < 2; ++it) {
            int f = t + 256 * it;          // 0..511
            int r = f >> 2;                // row 0..127
            int kq = f & 3;                // float4 within the 16-wide k strip
            float4 v = *reinterpret_cast<const float4*>(
                &A[(size_t)(m0 + r) * lda + k0 + kq * 4]);
            As[kq * 4 + 0][r] = v.x;
            As[kq * 4 + 1][r] = v.y;
            As[kq * 4 + 2][r] = v.z;
            As[kq * 4 + 3][r] = v.w;
        }
#pragma unroll
        for (int it = 0; it < 2; ++it) {
            int f = t + 256 * it;
            int r = f >> 5;                // k row 0..15
            int c4 = f & 31;               // float4 col
            *reinterpret_cast<float4*>(&Bs[r][c4 * 4]) =
                *reinterpret_cast<const float4*>(
                    &B[(size_t)(k0 + r) * ldb + n0 + c4 * 4]);
        }
        __syncthreads();
#pragma unroll
        for (int kk = 0; kk < 16; ++kk) {
            float a[8], b[8];
            *reinterpret_cast<float4*>(&a[0]) = *reinterpret_cast<const float4*>(&As[kk][ty * 4]);
            *reinterpret_cast<float4*>(&a[4]) = *reinterpret_cast<const float4*>(&As[kk][64 + ty * 4]);
            *reinterpret_cast<float4*>(&b[0]) = *reinterpret_cast<const float4*>(&Bs[kk][tx * 4]);
            *reinterpret_cast<float4*>(&b[4]) = *reinterpret_cast<const float4*>(&Bs[kk][64 + tx * 4]);
#pragma unroll
            for (int i = 0; i < 8; ++i)
#pragma unroll
                for (int j = 0; j < 8; ++j)
                    acc[i][j] = fmaf(a[i], b[j], acc[i][j]);
        }
        __syncthreads();
    }
#pragma unroll
    for (int ih = 0; ih < 2; ++ih)
#pragma unroll
        for (int i = 0; i < 4; ++i) {
            int row = m0 + ih * 64 + ty * 4 + i;
#pragma unroll
            for (int jh = 0; jh < 2; ++jh) {
                int col = n0 + jh * 64 + tx * 4;
                float4 bv = *reinterpret_cast<const float4*>(&bias[col]);
                float4 o;
                o.x = acc[ih*4+i][jh*4+0] + bv.x;
                o.y = acc[ih*4+i][jh*4+1] + bv.y;
                o.z = acc[ih*4+i][jh*4+2] + bv.z;
                o.w = acc[ih*4+i][jh*4+3] + bv.w;
                *reinterpret_cast<float4*>(&C[(size_t)row * ldc + col]) = o;
            }
        }
}

// Flash attention, fp32. One block per (b, h, 64-row q-tile).
// qkv layout: [B*T][2304] = [q(768) | k(768) | v(768)], head slice = 64 cols.
// Writes y into the q slice (each block owns its q rows+cols exclusively).
__global__ __launch_bounds__(256) void attn_fused(float* __restrict__ qkv)
{
    __shared__ float QsT[64][65];   // [d][r], pre-scaled by 1/8
    __shared__ float KsT[64][65];   // [d][c]
    __shared__ float Vs[64][64];    // [c][d]
    __shared__ float PsT[64][66];   // [c][r], pad 66 -> 4-way max on store

    const int qt = gridDim.x - 1 - blockIdx.x;   // heavy tiles first
    const int bh = blockIdx.y;
    const int b = bh / NHEAD, h = bh % NHEAD;
    const int t = threadIdx.x;
    const int tx = t & 15, ty = t >> 4;

    const size_t rowBase = (size_t)b * TSEQ;
    const int qOff = h * 64, kOff = CEMB + h * 64, vOff = 2 * CEMB + h * 64;

    // load Q tile (64 rows x 64 d), transposed + scaled
#pragma unroll
    for (int it = 0; it < 4; ++it) {
        int f = t + 256 * it;
        int r = f >> 4, d4 = f & 15;
        float4 v = *reinterpret_cast<const float4*>(
            &qkv[(rowBase + qt * 64 + r) * 2304 + qOff + d4 * 4]);
        QsT[d4*4+0][r] = v.x * 0.125f;
        QsT[d4*4+1][r] = v.y * 0.125f;
        QsT[d4*4+2][r] = v.z * 0.125f;
        QsT[d4*4+3][r] = v.w * 0.125f;
    }

    float mrow[4], lrow[4], o[4][4];
#pragma unroll
    for (int i = 0; i < 4; ++i) {
        mrow[i] = -1e30f; lrow[i] = 0.f;
#pragma unroll
        for (int j = 0; j < 4; ++j) o[i][j] = 0.f;
    }

    for (int kt = 0; kt <= qt; ++kt) {
        __syncthreads();   // prev PV (Vs,PsT reads) + prev S (KsT reads) done
#pragma unroll
        for (int it = 0; it < 4; ++it) {
            int f = t + 256 * it;
            int r = f >> 4, d4 = f & 15;
            size_t rowAddr = (rowBase + kt * 64 + r) * 2304;
            float4 kv = *reinterpret_cast<const float4*>(&qkv[rowAddr + kOff + d4 * 4]);
            KsT[d4*4+0][r] = kv.x;
            KsT[d4*4+1][r] = kv.y;
            KsT[d4*4+2][r] = kv.z;
            KsT[d4*4+3][r] = kv.w;
            *reinterpret_cast<float4*>(&Vs[r][d4 * 4]) =
                *reinterpret_cast<const float4*>(&qkv[rowAddr + vOff + d4 * 4]);
        }
        __syncthreads();

        // S[r][c] = (Q/8) @ K^T, 4x4 per thread: r = ty*4+i, c = tx*4+j
        float s[4][4];
#pragma unroll
        for (int i = 0; i < 4; ++i)
#pragma unroll
            for (int j = 0; j < 4; ++j) s[i][j] = 0.f;

#pragma unroll 8
        for (int d = 0; d < 64; ++d) {
            float aq[4], bk[4];
            *reinterpret_cast<float4*>(aq) = *reinterpret_cast<const float4*>(&QsT[d][ty * 4]);
            *reinterpret_cast<float4*>(bk) = *reinterpret_cast<const float4*>(&KsT[d][tx * 4]);
#pragma unroll
            for (int i = 0; i < 4; ++i)
#pragma unroll
                for (int j = 0; j < 4; ++j)
                    s[i][j] = fmaf(aq[i], bk[j], s[i][j]);
        }

        if (kt == qt) {      // only the diagonal tile needs causal masking
#pragma unroll
            for (int i = 0; i < 4; ++i)
#pragma unroll
                for (int j = 0; j < 4; ++j)
                    if (tx * 4 + j > ty * 4 + i) s[i][j] = -1e30f;
        }

        // online softmax update, per row
#pragma unroll
        for (int i = 0; i < 4; ++i) {
            float mx = fmaxf(fmaxf(s[i][0], s[i][1]), fmaxf(s[i][2], s[i][3]));
            mx = warp_max16(mx);
            float mnew = fmaxf(mrow[i], mx);
            float al = __expf(mrow[i] - mnew);
            float rs = 0.f;
#pragma unroll
            for (int j = 0; j < 4; ++j) {
                s[i][j] = __expf(s[i][j] - mnew);
                rs += s[i][j];
            }
            rs = warp_sum16(rs);
            lrow[i] = al * lrow[i] + rs;
            mrow[i] = mnew;
#pragma unroll
            for (int j = 0; j < 4; ++j) o[i][j] *= al;
        }

        // store P^T for the PV GEMM
#pragma unroll
        for (int j = 0; j < 4; ++j)
#pragma unroll
            for (int i = 0; i < 4; ++i)
                PsT[tx * 4 + j][ty * 4 + i] = s[i][j];
        __syncthreads();

        // O[r][d] += P @ V: r = ty*4+i, d = tx*4+j
#pragma unroll 8
        for (int c = 0; c < 64; ++c) {
            float ap[4], bv[4];
            *reinterpret_cast<float4*>(ap) = *reinterpret_cast<const float4*>(&PsT[c][ty * 4]);
            *reinterpret_cast<float4*>(bv) = *reinterpret_cast<const float4*>(&Vs[c][tx * 4]);
#pragma unroll
            for (int i = 0; i < 4; ++i)
#pragma unroll
                for (int j = 0; j < 4; ++j)
                    o[i][j] = fmaf(ap[i], bv[j], o[i][j]);
        }
    }

    // normalize and write y into the q slice
#pragma unroll
    for (int i = 0; i < 4; ++i) {
        float inv = 1.f / lrow[i];
        int r = ty * 4 + i;
        float4 out;
        out.x = o[i][0] * inv;
        out.y = o[i][1] * inv;
        out.z = o[i][2] * inv;
        out.w = o[i][3] * inv;
        *reinterpret_cast<float4*>(
            &qkv[(rowBase + qt * 64 + r) * 2304 + qOff + tx * 4]) = out;
    }
}

extern "C" void kernel_launch(void* const* d_in, const int* in_sizes, int n_in,
                              void* d_out, int out_size, void* d_ws, size_t ws_size,
                              hipStream_t stream)
{
    const float* x      = (const float*)d_in[0];
    const float* w_attn = (const float*)d_in[1];
    const float* b_attn = (const float*)d_in[2];
    const float* w_proj = (const float*)d_in[3];
    const float* b_proj = (const float*)d_in[4];
    float* out = (float*)d_out;
    float* qkv = (float*)d_ws;      // [8192][2304] fp32 = 75.5 MB

    const int M = 2 * TSEQ;         // 8192

    // qkv = x @ w_attn + b_attn   (M=8192, N=2304, K=768)
    gemm_bias<<<dim3(3 * CEMB / 128, M / 128), 256, 0, stream>>>(
        x, w_attn, b_attn, qkv, M, 3 * CEMB, CEMB, CEMB, 3 * CEMB, 3 * CEMB);

    // causal flash attention; writes y into q slice of qkv
    attn_fused<<<dim3(TSEQ / 64, 2 * NHEAD), 256, 0, stream>>>(qkv);

    // out = y @ w_proj + b_proj   (M=8192, N=768, K=768; y strided in qkv)
    gemm_bias<<<dim3(CEMB / 128, M / 128), 256, 0, stream>>>(
        qkv, w_proj, b_proj, out, M, CEMB, CEMB, 3 * CEMB, CEMB, CEMB);
}

// Round 2
// 793.074 us; speedup vs baseline: 2.6797x; 2.6797x over previous
//
#include <hip/hip_runtime.h>

#define TSEQ 4096
#define CEMB 768
#define NHEAD 12

using bf16x8 = __attribute__((ext_vector_type(8))) short;
using f32x4  = __attribute__((ext_vector_type(4))) float;

__device__ __forceinline__ unsigned int f2bf(float f) {
    unsigned int u = __float_as_uint(f);
    return (u + 0x7fffu + ((u >> 16) & 1u)) >> 16;   // RNE
}
__device__ __forceinline__ float warp_max16(float v) {
    v = fmaxf(v, __shfl_xor(v, 1));
    v = fmaxf(v, __shfl_xor(v, 2));
    v = fmaxf(v, __shfl_xor(v, 4));
    v = fmaxf(v, __shfl_xor(v, 8));
    return v;
}
__device__ __forceinline__ float warp_sum16(float v) {
    v += __shfl_xor(v, 1);
    v += __shfl_xor(v, 2);
    v += __shfl_xor(v, 4);
    v += __shfl_xor(v, 8);
    return v;
}

// ---------------- GEMM (fp32 compute, fp32 out) ----------------
__global__ __launch_bounds__(256) void gemm_bias(
    const float* __restrict__ A, const float* __restrict__ B,
    const float* __restrict__ bias, float* __restrict__ C,
    int M, int N, int K, int lda, int ldb, int ldc)
{
    __shared__ float As[16][132];
    __shared__ float Bs[16][128];
    const int t = threadIdx.x;
    const int tx = t & 15, ty = t >> 4;
    const int m0 = blockIdx.y * 128, n0 = blockIdx.x * 128;

    float acc[8][8];
#pragma unroll
    for (int i = 0; i < 8; ++i)
#pragma unroll
        for (int j = 0; j < 8; ++j) acc[i][j] = 0.f;

    for (int k0 = 0; k0 < K; k0 += 16) {
#pragma unroll
        for (int it = 0; it < 2; ++it) {
            int f = t + 256 * it;
            int r = f >> 2, kq = f & 3;
            float4 v = *reinterpret_cast<const float4*>(
                &A[(size_t)(m0 + r) * lda + k0 + kq * 4]);
            As[kq * 4 + 0][r] = v.x; As[kq * 4 + 1][r] = v.y;
            As[kq * 4 + 2][r] = v.z; As[kq * 4 + 3][r] = v.w;
        }
#pragma unroll
        for (int it = 0; it < 2; ++it) {
            int f = t + 256 * it;
            int r = f >> 5, c4 = f & 31;
            *reinterpret_cast<float4*>(&Bs[r][c4 * 4]) =
                *reinterpret_cast<const float4*>(&B[(size_t)(k0 + r) * ldb + n0 + c4 * 4]);
        }
        __syncthreads();
#pragma unroll
        for (int kk = 0; kk < 16; ++kk) {
            float a[8], b[8];
            *reinterpret_cast<float4*>(&a[0]) = *reinterpret_cast<const float4*>(&As[kk][ty * 4]);
            *reinterpret_cast<float4*>(&a[4]) = *reinterpret_cast<const float4*>(&As[kk][64 + ty * 4]);
            *reinterpret_cast<float4*>(&b[0]) = *reinterpret_cast<const float4*>(&Bs[kk][tx * 4]);
            *reinterpret_cast<float4*>(&b[4]) = *reinterpret_cast<const float4*>(&Bs[kk][64 + tx * 4]);
#pragma unroll
            for (int i = 0; i < 8; ++i)
#pragma unroll
                for (int j = 0; j < 8; ++j)
                    acc[i][j] = fmaf(a[i], b[j], acc[i][j]);
        }
        __syncthreads();
    }
#pragma unroll
    for (int ih = 0; ih < 2; ++ih)
#pragma unroll
        for (int i = 0; i < 4; ++i) {
            int row = m0 + ih * 64 + ty * 4 + i;
#pragma unroll
            for (int jh = 0; jh < 2; ++jh) {
                int col = n0 + jh * 64 + tx * 4;
                float4 bv = *reinterpret_cast<const float4*>(&bias[col]);
                float4 o;
                o.x = acc[ih*4+i][jh*4+0] + bv.x;
                o.y = acc[ih*4+i][jh*4+1] + bv.y;
                o.z = acc[ih*4+i][jh*4+2] + bv.z;
                o.w = acc[ih*4+i][jh*4+3] + bv.w;
                *reinterpret_cast<float4*>(&C[(size_t)row * ldc + col]) = o;
            }
        }
}

// ---------------- GEMM (fp32 compute, bf16 out; q columns pre-scaled by 1/8) ----------------
__global__ __launch_bounds__(256) void gemm_bias_bf16out(
    const float* __restrict__ A, const float* __restrict__ B,
    const float* __restrict__ bias, unsigned short* __restrict__ Cb,
    int M, int N, int K, int lda, int ldb, int ldc)
{
    __shared__ float As[16][132];
    __shared__ float Bs[16][128];
    const int t = threadIdx.x;
    const int tx = t & 15, ty = t >> 4;
    const int m0 = blockIdx.y * 128, n0 = blockIdx.x * 128;
    const float sc = (n0 < CEMB) ? 0.125f : 1.0f;   // fold 1/sqrt(64) into q

    float acc[8][8];
#pragma unroll
    for (int i = 0; i < 8; ++i)
#pragma unroll
        for (int j = 0; j < 8; ++j) acc[i][j] = 0.f;

    for (int k0 = 0; k0 < K; k0 += 16) {
#pragma unroll
        for (int it = 0; it < 2; ++it) {
            int f = t + 256 * it;
            int r = f >> 2, kq = f & 3;
            float4 v = *reinterpret_cast<const float4*>(
                &A[(size_t)(m0 + r) * lda + k0 + kq * 4]);
            As[kq * 4 + 0][r] = v.x; As[kq * 4 + 1][r] = v.y;
            As[kq * 4 + 2][r] = v.z; As[kq * 4 + 3][r] = v.w;
        }
#pragma unroll
        for (int it = 0; it < 2; ++it) {
            int f = t + 256 * it;
            int r = f >> 5, c4 = f & 31;
            *reinterpret_cast<float4*>(&Bs[r][c4 * 4]) =
                *reinterpret_cast<const float4*>(&B[(size_t)(k0 + r) * ldb + n0 + c4 * 4]);
        }
        __syncthreads();
#pragma unroll
        for (int kk = 0; kk < 16; ++kk) {
            float a[8], b[8];
            *reinterpret_cast<float4*>(&a[0]) = *reinterpret_cast<const float4*>(&As[kk][ty * 4]);
            *reinterpret_cast<float4*>(&a[4]) = *reinterpret_cast<const float4*>(&As[kk][64 + ty * 4]);
            *reinterpret_cast<float4*>(&b[0]) = *reinterpret_cast<const float4*>(&Bs[kk][tx * 4]);
            *reinterpret_cast<float4*>(&b[4]) = *reinterpret_cast<const float4*>(&Bs[kk][64 + tx * 4]);
#pragma unroll
            for (int i = 0; i < 8; ++i)
#pragma unroll
                for (int j = 0; j < 8; ++j)
                    acc[i][j] = fmaf(a[i], b[j], acc[i][j]);
        }
        __syncthreads();
    }
#pragma unroll
    for (int ih = 0; ih < 2; ++ih)
#pragma unroll
        for (int i = 0; i < 4; ++i) {
            int row = m0 + ih * 64 + ty * 4 + i;
#pragma unroll
            for (int jh = 0; jh < 2; ++jh) {
                int col = n0 + jh * 64 + tx * 4;
                float4 bv = *reinterpret_cast<const float4*>(&bias[col]);
                float v0 = (acc[ih*4+i][jh*4+0] + bv.x) * sc;
                float v1 = (acc[ih*4+i][jh*4+1] + bv.y) * sc;
                float v2 = (acc[ih*4+i][jh*4+2] + bv.z) * sc;
                float v3 = (acc[ih*4+i][jh*4+3] + bv.w) * sc;
                uint2 pk;
                pk.x = f2bf(v0) | (f2bf(v1) << 16);
                pk.y = f2bf(v2) | (f2bf(v3) << 16);
                *reinterpret_cast<uint2*>(&Cb[(size_t)row * ldc + col]) = pk;
            }
        }
}

// ---------------- V transpose: qkv bf16 [BT][2304] v-slice -> Vt [bh][64 d][4096 t] ----------------
__global__ __launch_bounds__(256) void vtrans(
    const unsigned short* __restrict__ qkvB, unsigned short* __restrict__ VtG)
{
    __shared__ unsigned short tile[64][66];
    const int t0 = blockIdx.x * 64;
    const int bh = blockIdx.y;
    const int b = bh / NHEAD, h = bh % NHEAD;
    const size_t rowBase = (size_t)b * TSEQ;
    const int tid = threadIdx.x;

#pragma unroll
    for (int it = 0; it < 2; ++it) {
        int f = tid + 256 * it;
        int r = f >> 3, s = f & 7;
        unsigned short tmp[8];
        *reinterpret_cast<uint4*>(tmp) = *reinterpret_cast<const uint4*>(
            &qkvB[(rowBase + t0 + r) * 2304 + 2 * CEMB + h * 64 + s * 8]);
#pragma unroll
        for (int j = 0; j < 8; ++j) tile[r][s * 8 + j] = tmp[j];
    }
    __syncthreads();
#pragma unroll
    for (int it = 0; it < 2; ++it) {
        int f = tid + 256 * it;
        int d = f >> 3, c = f & 7;
        unsigned short tmp[8];
#pragma unroll
        for (int j = 0; j < 8; ++j) tmp[j] = tile[c * 8 + j][d];
        *reinterpret_cast<uint4*>(&VtG[(size_t)bh * 64 * TSEQ + (size_t)d * TSEQ + t0 + c * 8]) =
            *reinterpret_cast<uint4*>(tmp);
    }
}

// ---------------- MFMA flash attention ----------------
// grid (T/64, B*H). block 256 = 4 waves; wave w owns q rows 16w..16w+15 of the tile.
__global__ __launch_bounds__(256) void attn_mfma(
    const unsigned short* __restrict__ qkvB,   // bf16 [8192][2304], q pre-scaled 1/8
    const unsigned short* __restrict__ VtG,    // bf16 [24][64][4096]
    float* __restrict__ Y)                     // fp32 [8192][768]
{
    __shared__ __align__(16) char Kl[8192];    // [kv 64][d 64] bf16, chunk-XOR swizzled
    __shared__ __align__(16) char Vl[8192];    // [d 64][kv 64] bf16, swizzled
    __shared__ __align__(16) char Pl[8192];    // 4 waves x [q 16][kv 64] bf16, swizzled

    const int qt = gridDim.x - 1 - blockIdx.x;   // heavy tiles first
    const int bh = blockIdx.y;
    const int b = bh / NHEAD, h = bh % NHEAD;
    const int tid = threadIdx.x;
    const int w = tid >> 6;
    const int lane = tid & 63;
    const int g = lane >> 4, lq = lane & 15;

    const size_t rowBase = (size_t)b * TSEQ;
    const unsigned short* Vhead = VtG + (size_t)bh * 64 * TSEQ;

    // Q fragments (persist): lane holds Q[16w+lq][32*dt+8g+j]
    bf16x8 qf[2];
    {
        const size_t qrow = rowBase + (size_t)qt * 64 + 16 * w + lq;
#pragma unroll
        for (int dt = 0; dt < 2; ++dt)
            qf[dt] = *reinterpret_cast<const bf16x8*>(
                &qkvB[qrow * 2304 + h * 64 + 32 * dt + 8 * g]);
    }

    f32x4 ofr[4];
    float mrow[4], lrow[4];
#pragma unroll
    for (int r = 0; r < 4; ++r) { mrow[r] = -1e30f; lrow[r] = 0.f; }
#pragma unroll
    for (int dt = 0; dt < 4; ++dt) ofr[dt] = (f32x4){0.f, 0.f, 0.f, 0.f};

    char* Pw = Pl + w * 2048;

    for (int kt = 0; kt <= qt; ++kt) {
        // ---- stage K tile and Vt tile (bf16, swizzled) ----
#pragma unroll
        for (int it = 0; it < 2; ++it) {
            int f = tid + 256 * it;          // 0..511 : 16B chunks
            int r = f >> 3, s = f & 7;
            uint4 kq = *reinterpret_cast<const uint4*>(
                &qkvB[(rowBase + (size_t)kt * 64 + r) * 2304 + CEMB + h * 64 + s * 8]);
            *reinterpret_cast<uint4*>(Kl + r * 128 + ((s ^ (r & 7)) << 4)) = kq;
            uint4 vq = *reinterpret_cast<const uint4*>(
                &Vhead[(size_t)r * TSEQ + (size_t)kt * 64 + s * 8]);
            *reinterpret_cast<uint4*>(Vl + r * 128 + ((s ^ (r & 7)) << 4)) = vq;
        }
        __syncthreads();

        // ---- S = Q K^T  (4 col-tiles x (2 chained K=32 MFMAs)) ----
        f32x4 sfr[4];
#pragma unroll
        for (int c = 0; c < 4; ++c) {
            const int kvr = 16 * c + lq;
            const int xr = lq & 7;
            bf16x8 k0 = *reinterpret_cast<const bf16x8*>(Kl + kvr * 128 + ((g ^ xr) << 4));
            bf16x8 k1 = *reinterpret_cast<const bf16x8*>(Kl + kvr * 128 + (((4 + g) ^ xr) << 4));
            f32x4 acc = (f32x4){0.f, 0.f, 0.f, 0.f};
            acc = __builtin_amdgcn_mfma_f32_16x16x32_bf16(qf[0], k0, acc, 0, 0, 0);
            acc = __builtin_amdgcn_mfma_f32_16x16x32_bf16(qf[1], k1, acc, 0, 0, 0);
            sfr[c] = acc;
        }

        if (kt == qt) {   // causal mask on the diagonal tile
            const int qp = 16 * w + 4 * g;
#pragma unroll
            for (int c = 0; c < 4; ++c) {
                const int kp = 16 * c + lq;
#pragma unroll
                for (int r = 0; r < 4; ++r)
                    if (kp > qp + r) sfr[c][r] = -1e30f;
            }
        }

        // ---- online softmax (rows live in 16-lane groups) ----
#pragma unroll
        for (int r = 0; r < 4; ++r) {
            float mx = fmaxf(fmaxf(sfr[0][r], sfr[1][r]), fmaxf(sfr[2][r], sfr[3][r]));
            mx = warp_max16(mx);
            float mnew = fmaxf(mrow[r], mx);
            float al = __expf(mrow[r] - mnew);
            float rs = 0.f;
#pragma unroll
            for (int c = 0; c < 4; ++c) {
                float p = __expf(sfr[c][r] - mnew);
                sfr[c][r] = p;
                rs += p;
            }
            rs = warp_sum16(rs);
            lrow[r] = al * lrow[r] + rs;
            mrow[r] = mnew;
#pragma unroll
            for (int dt = 0; dt < 4; ++dt) ofr[dt][r] *= al;
        }

        // ---- P -> per-wave LDS (bf16, swizzled); wave-private, no barrier ----
#pragma unroll
        for (int c = 0; c < 4; ++c) {
            const int kp = 16 * c + lq;
#pragma unroll
            for (int r = 0; r < 4; ++r) {
                const int qp = 4 * g + r;
                const int byte = qp * 128 + (((kp >> 3) ^ (qp & 7)) << 4) + (kp & 7) * 2;
                *reinterpret_cast<unsigned short*>(Pw + byte) = (unsigned short)f2bf(sfr[c][r]);
            }
        }

        // ---- O += P V ----
#pragma unroll
        for (int ktile = 0; ktile < 2; ++ktile) {
            bf16x8 pf = *reinterpret_cast<const bf16x8*>(
                Pw + lq * 128 + (((4 * ktile + g) ^ (lq & 7)) << 4));
#pragma unroll
            for (int dt = 0; dt < 4; ++dt) {
                const int d = 16 * dt + lq;
                bf16x8 vf = *reinterpret_cast<const bf16x8*>(
                    Vl + d * 128 + (((4 * ktile + g) ^ (d & 7)) << 4));
                ofr[dt] = __builtin_amdgcn_mfma_f32_16x16x32_bf16(pf, vf, ofr[dt], 0, 0, 0);
            }
        }
        __syncthreads();   // protect Kl/Vl before next stage
    }

    // ---- normalize + write y (fp32) ----
#pragma unroll
    for (int r = 0; r < 4; ++r) {
        const float inv = 1.f / lrow[r];
        const size_t row = rowBase + (size_t)qt * 64 + 16 * w + 4 * g + r;
#pragma unroll
        for (int dt = 0; dt < 4; ++dt)
            Y[row * CEMB + h * 64 + 16 * dt + lq] = ofr[dt][r] * inv;
    }
}

extern "C" void kernel_launch(void* const* d_in, const int* in_sizes, int n_in,
                              void* d_out, int out_size, void* d_ws, size_t ws_size,
                              hipStream_t stream)
{
    const float* x      = (const float*)d_in[0];
    const float* w_attn = (const float*)d_in[1];
    const float* b_attn = (const float*)d_in[2];
    const float* w_proj = (const float*)d_in[3];
    const float* b_proj = (const float*)d_in[4];
    float* out = (float*)d_out;

    const int M = 2 * TSEQ;  // 8192
    unsigned short* qkvB = (unsigned short*)d_ws;                       // 37,748,736 B
    unsigned short* VtG  = (unsigned short*)((char*)d_ws + 37748736);   // 12,582,912 B
    float*          Y    = (float*)((char*)d_ws + 50331648);            // 25,165,824 B

    // qkv = x @ w_attn + b_attn  -> bf16 (q pre-scaled by 1/8)
    gemm_bias_bf16out<<<dim3(3 * CEMB / 128, M / 128), 256, 0, stream>>>(
        x, w_attn, b_attn, qkvB, M, 3 * CEMB, CEMB, CEMB, 3 * CEMB, 3 * CEMB);

    // V -> Vt [bh][d][t]
    vtrans<<<dim3(TSEQ / 64, 2 * NHEAD), 256, 0, stream>>>(qkvB, VtG);

    // flash attention (MFMA bf16) -> Y fp32
    attn_mfma<<<dim3(TSEQ / 64, 2 * NHEAD), 256, 0, stream>>>(qkvB, VtG, Y);

    // out = Y @ w_proj + b_proj (fp32)
    gemm_bias<<<dim3(CEMB / 128, M / 128), 256, 0, stream>>>(
        Y, w_proj, b_proj, out, M, CEMB, CEMB, CEMB, CEMB, CEMB);
}

// Round 3
// 358.699 us; speedup vs baseline: 5.9247x; 2.2110x over previous
//
#include <hip/hip_runtime.h>

#define TSEQ 4096
#define CEMB 768
#define NHEAD 12

using bf16x8 = __attribute__((ext_vector_type(8))) short;
using f32x4  = __attribute__((ext_vector_type(4))) float;

__device__ __forceinline__ unsigned int f2bf(float f) {
    unsigned int u = __float_as_uint(f);
    return (u + 0x7fffu + ((u >> 16) & 1u)) >> 16;   // RNE
}
__device__ __forceinline__ void async_cp16(void* lds, const void* g) {
    __builtin_amdgcn_global_load_lds(
        (const __attribute__((address_space(1))) void*)g,
        (__attribute__((address_space(3))) void*)lds, 16, 0, 0);
}
__device__ __forceinline__ float warp_max16(float v) {
    v = fmaxf(v, __shfl_xor(v, 1));
    v = fmaxf(v, __shfl_xor(v, 2));
    v = fmaxf(v, __shfl_xor(v, 4));
    v = fmaxf(v, __shfl_xor(v, 8));
    return v;
}
__device__ __forceinline__ float warp_sum16(float v) {
    v += __shfl_xor(v, 1);
    v += __shfl_xor(v, 2);
    v += __shfl_xor(v, 4);
    v += __shfl_xor(v, 8);
    return v;
}

// ---------------- x fp32 -> bf16 ----------------
__global__ __launch_bounds__(256) void cvt_bf16(
    const float* __restrict__ X, unsigned short* __restrict__ Xb, int n8)
{
    int i = blockIdx.x * 256 + threadIdx.x;
    if (i >= n8) return;
    float4 a = *reinterpret_cast<const float4*>(&X[(size_t)i * 8]);
    float4 b = *reinterpret_cast<const float4*>(&X[(size_t)i * 8 + 4]);
    uint2 lo, hi;
    lo.x = f2bf(a.x) | (f2bf(a.y) << 16);
    lo.y = f2bf(a.z) | (f2bf(a.w) << 16);
    hi.x = f2bf(b.x) | (f2bf(b.y) << 16);
    hi.y = f2bf(b.z) | (f2bf(b.w) << 16);
    uint4 o = make_uint4(lo.x, lo.y, hi.x, hi.y);
    *reinterpret_cast<uint4*>(&Xb[(size_t)i * 8]) = o;
}

// ---------------- W fp32 [K][N] -> bf16 [N][K] ----------------
__global__ __launch_bounds__(256) void wtrans(
    const float* __restrict__ W, unsigned short* __restrict__ WT, int K, int N)
{
    __shared__ unsigned short tile[64][72];
    const int k0 = blockIdx.y * 64, n0 = blockIdx.x * 64;
    const int tid = threadIdx.x;
#pragma unroll
    for (int it = 0; it < 4; ++it) {
        int f = tid + it * 256;          // 0..1023 float4s
        int r = f >> 4, c4 = f & 15;
        float4 v = *reinterpret_cast<const float4*>(&W[(size_t)(k0 + r) * N + n0 + c4 * 4]);
        tile[r][c4 * 4 + 0] = (unsigned short)f2bf(v.x);
        tile[r][c4 * 4 + 1] = (unsigned short)f2bf(v.y);
        tile[r][c4 * 4 + 2] = (unsigned short)f2bf(v.z);
        tile[r][c4 * 4 + 3] = (unsigned short)f2bf(v.w);
    }
    __syncthreads();
#pragma unroll
    for (int it = 0; it < 2; ++it) {
        int f = tid + it * 256;          // 0..511
        int rn = f >> 3, c8 = f & 7;
        unsigned short tmp[8];
#pragma unroll
        for (int j = 0; j < 8; ++j) tmp[j] = tile[c8 * 8 + j][rn];
        *reinterpret_cast<uint4*>(&WT[(size_t)(n0 + rn) * K + k0 + c8 * 8]) =
            *reinterpret_cast<uint4*>(tmp);
    }
}

// ---------------- bf16 MFMA GEMM: C[m][n] = A[m][k] * BT[n][k] + bias ----------------
// 128x128 tile, BK=64, 256 threads = 4 waves, each wave 64x64 out.
template<int BF16OUT, int QSCALE>
__global__ __launch_bounds__(256) void gemm_mfma(
    const unsigned short* __restrict__ A,    // [M][K] bf16
    const unsigned short* __restrict__ BT,   // [N][K] bf16
    const float* __restrict__ bias,          // [N]
    void* __restrict__ Cv,                   // bf16 or fp32 [M][N]
    int M, int N, int K)
{
    __shared__ __align__(16) unsigned short As[128 * 64];
    __shared__ __align__(16) unsigned short Bs[128 * 64];

    const int nwg = gridDim.x * gridDim.y;
    const int id = blockIdx.y * gridDim.x + blockIdx.x;
    const int qx = nwg >> 3;                          // grid is a multiple of 8
    const int swz = (id & 7) * qx + (id >> 3);
    const int nb = N >> 7;
    const int m0 = (swz / nb) * 128, n0 = (swz % nb) * 128;

    const int tid = threadIdx.x;
    const int w = tid >> 6, lane = tid & 63;
    const int wr = w >> 1, wc = w & 1;
    const int lq = lane & 15, g = lane >> 4;
    const int wrOff = wr * 64, wcOff = wc * 64;

    f32x4 acc[4][4];
#pragma unroll
    for (int i = 0; i < 4; ++i)
#pragma unroll
        for (int j = 0; j < 4; ++j) acc[i][j] = (f32x4){0.f, 0.f, 0.f, 0.f};

    for (int k0 = 0; k0 < K; k0 += 64) {
        // stage A,B tiles: linear LDS dest, inverse-swizzled global source
#pragma unroll
        for (int it = 0; it < 4; ++it) {
            const int dbase = it * 256 + w * 64;
            const int d = dbase + lane;
            const int r = d >> 3;
            const int s = (d & 7) ^ (r & 7);
            async_cp16((char*)As + dbase * 16, A + (size_t)(m0 + r) * K + k0 + s * 8);
            async_cp16((char*)Bs + dbase * 16, BT + (size_t)(n0 + r) * K + k0 + s * 8);
        }
        __syncthreads();

#pragma unroll
        for (int kk = 0; kk < 2; ++kk) {
            bf16x8 af[4], bfr[4];
#pragma unroll
            for (int i = 0; i < 4; ++i) {
                const int ra = wrOff + i * 16 + lq;
                af[i] = *reinterpret_cast<const bf16x8*>(
                    (char*)As + ra * 128 + (((kk * 4 + g) ^ (ra & 7)) << 4));
                const int rb = wcOff + i * 16 + lq;
                bfr[i] = *reinterpret_cast<const bf16x8*>(
                    (char*)Bs + rb * 128 + (((kk * 4 + g) ^ (rb & 7)) << 4));
            }
#pragma unroll
            for (int i = 0; i < 4; ++i)
#pragma unroll
                for (int j = 0; j < 4; ++j)
                    acc[i][j] = __builtin_amdgcn_mfma_f32_16x16x32_bf16(
                        af[i], bfr[j], acc[i][j], 0, 0, 0);
        }
        __syncthreads();
    }

#pragma unroll
    for (int i = 0; i < 4; ++i)
#pragma unroll
        for (int j = 0; j < 4; ++j) {
            const int col = n0 + wcOff + j * 16 + lq;
            const float bv = bias[col];
            const float scl = (QSCALE && col < CEMB) ? 0.125f : 1.0f;
#pragma unroll
            for (int rg = 0; rg < 4; ++rg) {
                const int row = m0 + wrOff + i * 16 + g * 4 + rg;
                const float v = (acc[i][j][rg] + bv) * scl;
                if (BF16OUT)
                    ((unsigned short*)Cv)[(size_t)row * N + col] = (unsigned short)f2bf(v);
                else
                    ((float*)Cv)[(size_t)row * N + col] = v;
            }
        }
}

// ---------------- V transpose: qkv bf16 v-slice -> Vt [bh][64 d][4096 t] ----------------
__global__ __launch_bounds__(256) void vtrans(
    const unsigned short* __restrict__ qkvB, unsigned short* __restrict__ VtG)
{
    __shared__ unsigned short tile[64][66];
    const int t0 = blockIdx.x * 64;
    const int bh = blockIdx.y;
    const int b = bh / NHEAD, h = bh % NHEAD;
    const size_t rowBase = (size_t)b * TSEQ;
    const int tid = threadIdx.x;

#pragma unroll
    for (int it = 0; it < 2; ++it) {
        int f = tid + 256 * it;
        int r = f >> 3, s = f & 7;
        unsigned short tmp[8];
        *reinterpret_cast<uint4*>(tmp) = *reinterpret_cast<const uint4*>(
            &qkvB[(rowBase + t0 + r) * 2304 + 2 * CEMB + h * 64 + s * 8]);
#pragma unroll
        for (int j = 0; j < 8; ++j) tile[r][s * 8 + j] = tmp[j];
    }
    __syncthreads();
#pragma unroll
    for (int it = 0; it < 2; ++it) {
        int f = tid + 256 * it;
        int d = f >> 3, c = f & 7;
        unsigned short tmp[8];
#pragma unroll
        for (int j = 0; j < 8; ++j) tmp[j] = tile[c * 8 + j][d];
        *reinterpret_cast<uint4*>(&VtG[(size_t)bh * 64 * TSEQ + (size_t)d * TSEQ + t0 + c * 8]) =
            *reinterpret_cast<uint4*>(tmp);
    }
}

// ---------------- MFMA flash attention -> Y bf16 ----------------
__global__ __launch_bounds__(256) void attn_mfma(
    const unsigned short* __restrict__ qkvB,   // bf16 [8192][2304], q pre-scaled 1/8
    const unsigned short* __restrict__ VtG,    // bf16 [24][64][4096]
    unsigned short* __restrict__ Yb)           // bf16 [8192][768]
{
    __shared__ __align__(16) char Kl[8192];
    __shared__ __align__(16) char Vl[8192];
    __shared__ __align__(16) char Pl[8192];

    const int qt = gridDim.x - 1 - blockIdx.x;
    const int bh = blockIdx.y;
    const int b = bh / NHEAD, h = bh % NHEAD;
    const int tid = threadIdx.x;
    const int w = tid >> 6;
    const int lane = tid & 63;
    const int g = lane >> 4, lq = lane & 15;

    const size_t rowBase = (size_t)b * TSEQ;
    const unsigned short* Vhead = VtG + (size_t)bh * 64 * TSEQ;

    bf16x8 qf[2];
    {
        const size_t qrow = rowBase + (size_t)qt * 64 + 16 * w + lq;
#pragma unroll
        for (int dt = 0; dt < 2; ++dt)
            qf[dt] = *reinterpret_cast<const bf16x8*>(
                &qkvB[qrow * 2304 + h * 64 + 32 * dt + 8 * g]);
    }

    f32x4 ofr[4];
    float mrow[4], lrow[4];
#pragma unroll
    for (int r = 0; r < 4; ++r) { mrow[r] = -1e30f; lrow[r] = 0.f; }
#pragma unroll
    for (int dt = 0; dt < 4; ++dt) ofr[dt] = (f32x4){0.f, 0.f, 0.f, 0.f};

    char* Pw = Pl + w * 2048;

    for (int kt = 0; kt <= qt; ++kt) {
#pragma unroll
        for (int it = 0; it < 2; ++it) {
            int f = tid + 256 * it;
            int r = f >> 3, s = f & 7;
            uint4 kq = *reinterpret_cast<const uint4*>(
                &qkvB[(rowBase + (size_t)kt * 64 + r) * 2304 + CEMB + h * 64 + s * 8]);
            *reinterpret_cast<uint4*>(Kl + r * 128 + ((s ^ (r & 7)) << 4)) = kq;
            uint4 vq = *reinterpret_cast<const uint4*>(
                &Vhead[(size_t)r * TSEQ + (size_t)kt * 64 + s * 8]);
            *reinterpret_cast<uint4*>(Vl + r * 128 + ((s ^ (r & 7)) << 4)) = vq;
        }
        __syncthreads();

        f32x4 sfr[4];
#pragma unroll
        for (int c = 0; c < 4; ++c) {
            const int kvr = 16 * c + lq;
            const int xr = lq & 7;
            bf16x8 k0 = *reinterpret_cast<const bf16x8*>(Kl + kvr * 128 + ((g ^ xr) << 4));
            bf16x8 k1 = *reinterpret_cast<const bf16x8*>(Kl + kvr * 128 + (((4 + g) ^ xr) << 4));
            f32x4 a0 = (f32x4){0.f, 0.f, 0.f, 0.f};
            a0 = __builtin_amdgcn_mfma_f32_16x16x32_bf16(qf[0], k0, a0, 0, 0, 0);
            a0 = __builtin_amdgcn_mfma_f32_16x16x32_bf16(qf[1], k1, a0, 0, 0, 0);
            sfr[c] = a0;
        }

        if (kt == qt) {
            const int qp = 16 * w + 4 * g;
#pragma unroll
            for (int c = 0; c < 4; ++c) {
                const int kp = 16 * c + lq;
#pragma unroll
                for (int r = 0; r < 4; ++r)
                    if (kp > qp + r) sfr[c][r] = -1e30f;
            }
        }

#pragma unroll
        for (int r = 0; r < 4; ++r) {
            float mx = fmaxf(fmaxf(sfr[0][r], sfr[1][r]), fmaxf(sfr[2][r], sfr[3][r]));
            mx = warp_max16(mx);
            float mnew = fmaxf(mrow[r], mx);
            float al = __expf(mrow[r] - mnew);
            float rs = 0.f;
#pragma unroll
            for (int c = 0; c < 4; ++c) {
                float p = __expf(sfr[c][r] - mnew);
                sfr[c][r] = p;
                rs += p;
            }
            rs = warp_sum16(rs);
            lrow[r] = al * lrow[r] + rs;
            mrow[r] = mnew;
#pragma unroll
            for (int dt = 0; dt < 4; ++dt) ofr[dt][r] *= al;
        }

#pragma unroll
        for (int c = 0; c < 4; ++c) {
            const int kp = 16 * c + lq;
#pragma unroll
            for (int r = 0; r < 4; ++r) {
                const int qp = 4 * g + r;
                const int byte = qp * 128 + (((kp >> 3) ^ (qp & 7)) << 4) + (kp & 7) * 2;
                *reinterpret_cast<unsigned short*>(Pw + byte) = (unsigned short)f2bf(sfr[c][r]);
            }
        }

#pragma unroll
        for (int ktile = 0; ktile < 2; ++ktile) {
            bf16x8 pf = *reinterpret_cast<const bf16x8*>(
                Pw + lq * 128 + (((4 * ktile + g) ^ (lq & 7)) << 4));
#pragma unroll
            for (int dt = 0; dt < 4; ++dt) {
                const int d = 16 * dt + lq;
                bf16x8 vf = *reinterpret_cast<const bf16x8*>(
                    Vl + d * 128 + (((4 * ktile + g) ^ (d & 7)) << 4));
                ofr[dt] = __builtin_amdgcn_mfma_f32_16x16x32_bf16(pf, vf, ofr[dt], 0, 0, 0);
            }
        }
        __syncthreads();
    }

#pragma unroll
    for (int r = 0; r < 4; ++r) {
        const float inv = 1.f / lrow[r];
        const size_t row = rowBase + (size_t)qt * 64 + 16 * w + 4 * g + r;
#pragma unroll
        for (int dt = 0; dt < 4; ++dt)
            Yb[row * CEMB + h * 64 + 16 * dt + lq] =
                (unsigned short)f2bf(ofr[dt][r] * inv);
    }
}

extern "C" void kernel_launch(void* const* d_in, const int* in_sizes, int n_in,
                              void* d_out, int out_size, void* d_ws, size_t ws_size,
                              hipStream_t stream)
{
    const float* x      = (const float*)d_in[0];
    const float* w_attn = (const float*)d_in[1];
    const float* b_attn = (const float*)d_in[2];
    const float* w_proj = (const float*)d_in[3];
    const float* b_proj = (const float*)d_in[4];
    float* out = (float*)d_out;

    const int M = 2 * TSEQ;  // 8192
    char* ws = (char*)d_ws;
    unsigned short* qkvB = (unsigned short*)ws;                   // 37,748,736 B
    unsigned short* VtG  = (unsigned short*)(ws + 37748736);      // 12,582,912 B
    unsigned short* xYb  = (unsigned short*)(ws + 50331648);      // 12,582,912 B (xB, then Yb)
    unsigned short* wT   = (unsigned short*)(ws + 62914560);      //  3,538,944 B
    unsigned short* wpT  = (unsigned short*)(ws + 66453504);      //  1,179,648 B

    // x -> bf16
    cvt_bf16<<<dim3((M * CEMB) / 8 / 256), 256, 0, stream>>>(x, xYb, (M * CEMB) / 8);
    // weights -> bf16, transposed [N][K]
    wtrans<<<dim3(3 * CEMB / 64, CEMB / 64), 256, 0, stream>>>(w_attn, wT, CEMB, 3 * CEMB);
    wtrans<<<dim3(CEMB / 64, CEMB / 64), 256, 0, stream>>>(w_proj, wpT, CEMB, CEMB);

    // qkv = x @ w_attn + b_attn -> bf16 (q pre-scaled 1/8)
    gemm_mfma<1, 1><<<dim3(3 * CEMB / 128, M / 128), 256, 0, stream>>>(
        xYb, wT, b_attn, qkvB, M, 3 * CEMB, CEMB);

    // V -> Vt [bh][d][t]
    vtrans<<<dim3(TSEQ / 64, 2 * NHEAD), 256, 0, stream>>>(qkvB, VtG);

    // flash attention -> Y bf16 (overwrites xB, dead after gemm1)
    attn_mfma<<<dim3(TSEQ / 64, 2 * NHEAD), 256, 0, stream>>>(qkvB, VtG, xYb);

    // out = Y @ w_proj + b_proj (fp32 out)
    gemm_mfma<0, 0><<<dim3(CEMB / 128, M / 128), 256, 0, stream>>>(
        xYb, wpT, b_proj, out, M, CEMB, CEMB);
}